// Round 1
// baseline (230.124 us; speedup 1.0000x reference)
//
#include <hip/hip_runtime.h>
#include <hip/hip_bf16.h>
#include <cstdint>
#include <cstddef>

typedef __attribute__((ext_vector_type(4))) float f32x4;
typedef __attribute__((ext_vector_type(8))) short s16x8;
typedef __attribute__((ext_vector_type(4))) unsigned short u16x4;
typedef __attribute__((ext_vector_type(8))) unsigned short u16x8;

#define NB 32
#define DD 512
#define TT 4096
#define HH 512
#define LDA 72  // padded bf16 stride: 144B/row => even bank spread for b128 frag reads

__device__ __forceinline__ unsigned short f2bf(float f) {
  uint32_t u = __builtin_bit_cast(uint32_t, f);
  u += 0x7fffu + ((u >> 16) & 1u);   // RNE; inputs are normal floats
  return (unsigned short)(u >> 16);
}

__device__ __forceinline__ float tanh_fast(float x) {
  x = fminf(fmaxf(x, -15.f), 15.f);
  float e = __expf(2.f * x);
  return (e - 1.f) / (e + 1.f);
}

// --- A1: convert W1 = w42[:, :512] to bf16 (row-major [512][512]) ---
__global__ void kConv(const float* __restrict__ w42, unsigned short* __restrict__ W1bf) {
  int e4 = (blockIdx.x * 256 + threadIdx.x) * 4;
  int h = e4 >> 9, d = e4 & 511;
  f32x4 v = *reinterpret_cast<const f32x4*>(&w42[h * 1024 + d]);
  u16x4 o;
  o[0] = f2bf(v.x); o[1] = f2bf(v.y); o[2] = f2bf(v.z); o[3] = f2bf(v.w);
  *reinterpret_cast<u16x4*>(&W1bf[h * 512 + d]) = o;
}

// --- A2: qterm[b,h] = w42[h,512:]·query[b] + b4[h]  (one wave per (b,h)) ---
__global__ void kQterm(const float* __restrict__ w42, const float* __restrict__ query,
                       const float* __restrict__ b4, float* __restrict__ qterm) {
  int wid = blockIdx.x * 4 + (threadIdx.x >> 6);
  int lane = threadIdx.x & 63;
  int b = wid >> 9, h = wid & 511;
  const float* wr = &w42[h * 1024 + 512];
  const float* q  = &query[b * 512];
  int d = lane * 8;
  f32x4 w0 = *(const f32x4*)&wr[d], w1 = *(const f32x4*)&wr[d + 4];
  f32x4 q0 = *(const f32x4*)&q[d],  q1 = *(const f32x4*)&q[d + 4];
  float s = w0.x*q0.x + w0.y*q0.y + w0.z*q0.z + w0.w*q0.w
          + w1.x*q1.x + w1.y*q1.y + w1.z*q1.z + w1.w*q1.w;
  #pragma unroll
  for (int off = 32; off; off >>= 1) s += __shfl_xor(s, off);
  if (lane == 0) qterm[b * 512 + h] = s + b4[h];
}

// --- B: fused  n5p[hblk][b][t] = sum_{h in hblk} w54[h]*tanh(W1@keys + qterm) ---
__global__ __launch_bounds__(256) void kMain(
    const float* __restrict__ keys, const unsigned short* __restrict__ W1bf,
    const float* __restrict__ qterm, const float* __restrict__ w54,
    float* __restrict__ n5p) {
  __shared__ unsigned short As[128][LDA];    // 18432 B
  __shared__ unsigned short Bs[8][128][8];   // 16384 B, [kg][t-slot][k%8], slot=(t+2kg)&127
  __shared__ float red[2][128];

  int p = blockIdx.x;
  int lix = (p & 7) * 512 + (p >> 3);        // XCD swizzle: 4 h-siblings land on one XCD
  int hblk = lix & 3, tblk = (lix >> 2) & 31, b = lix >> 7;
  int h0 = hblk * 128, t0 = tblk * 128;

  int tid = threadIdx.x;
  int lane = tid & 63, wid = tid >> 6;
  int wm = wid >> 1, wn = wid & 1;
  int lr = lane & 15, lg = lane >> 4;

  f32x4 zero = {0.f, 0.f, 0.f, 0.f};
  f32x4 acc[4][4];
  #pragma unroll
  for (int m = 0; m < 4; ++m)
    #pragma unroll
    for (int n = 0; n < 4; ++n) acc[m][n] = zero;

  const size_t keyb = (size_t)b * DD * TT;

  for (int kk = 0; kk < 8; ++kk) {
    int k0 = kk * 64;
    // stage A tile: 128 x 64 bf16 (8B per thread per iter, coalesced)
    #pragma unroll
    for (int i = 0; i < 8; ++i) {
      int e = tid + i * 256;
      int r = e >> 4, c4 = (e & 15) * 4;
      u16x4 v = *reinterpret_cast<const u16x4*>(&W1bf[(h0 + r) * 512 + k0 + c4]);
      *reinterpret_cast<u16x4*>(&As[r][c4]) = v;
    }
    // stage B tile: keys f32 [64k][128t] -> bf16, kg-interleaved, rotated slots
    #pragma unroll
    for (int i = 0; i < 4; ++i) {
      int e = tid + i * 256;
      int t = e & 127, kg = e >> 7;
      const float* src = &keys[keyb + (size_t)(k0 + kg * 8) * TT + t0 + t];
      u16x8 o;
      #pragma unroll
      for (int j = 0; j < 8; ++j) o[j] = f2bf(src[(size_t)j * TT]);
      int s = (t + 2 * kg) & 127;
      *reinterpret_cast<u16x8*>(&Bs[kg][s][0]) = o;
    }
    __syncthreads();
    #pragma unroll
    for (int ss = 0; ss < 2; ++ss) {
      s16x8 a[4], bb[4];
      #pragma unroll
      for (int m = 0; m < 4; ++m)
        a[m] = *reinterpret_cast<const s16x8*>(&As[wm * 64 + m * 16 + lr][ss * 32 + lg * 8]);
      #pragma unroll
      for (int n = 0; n < 4; ++n) {
        int kg = ss * 4 + lg;
        int col = wn * 64 + n * 16 + lr;
        int s = (col + 2 * kg) & 127;
        bb[n] = *reinterpret_cast<const s16x8*>(&Bs[kg][s][0]);
      }
      #pragma unroll
      for (int m = 0; m < 4; ++m)
        #pragma unroll
        for (int n = 0; n < 4; ++n)
          acc[m][n] = __builtin_amdgcn_mfma_f32_16x16x32_bf16(a[m], bb[n], acc[m][n], 0, 0, 0);
    }
    __syncthreads();
  }

  // epilogue: tanh + w54-weighted reduce over this block's 128 h
  float part[4] = {0.f, 0.f, 0.f, 0.f};
  #pragma unroll
  for (int m = 0; m < 4; ++m) {
    #pragma unroll
    for (int r = 0; r < 4; ++r) {
      int h = h0 + wm * 64 + m * 16 + lg * 4 + r;   // C/D: row=(lane>>4)*4+reg
      float qv = qterm[b * HH + h];
      float wv = w54[h];
      #pragma unroll
      for (int n = 0; n < 4; ++n)
        part[n] += wv * tanh_fast(acc[m][n][r] + qv);
    }
  }
  #pragma unroll
  for (int n = 0; n < 4; ++n) {
    part[n] += __shfl_xor(part[n], 16);
    part[n] += __shfl_xor(part[n], 32);
  }
  if (lane < 16) {
    #pragma unroll
    for (int n = 0; n < 4; ++n) red[wm][wn * 64 + n * 16 + lane] = part[n];
  }
  __syncthreads();
  if (tid < 128) {
    float v = red[0][tid] + red[1][tid];
    n5p[((size_t)hblk * NB + b) * TT + t0 + tid] = v;
  }
}

// --- C: softmax over T per batch (b5 cancels in softmax; omitted) ---
__global__ void kSoftmax(const float* __restrict__ n5p, float* __restrict__ a5) {
  int b = blockIdx.x, tid = threadIdx.x;
  int lane = tid & 63, wid = tid >> 6;
  __shared__ float sm[4];
  __shared__ float ssum[4];
  float vals[16];
  float mx = -1e30f;
  #pragma unroll
  for (int i = 0; i < 16; ++i) {
    int t = tid + i * 256;
    float v = n5p[(0 * NB + b) * TT + t] + n5p[(1 * NB + b) * TT + t]
            + n5p[(2 * NB + b) * TT + t] + n5p[(3 * NB + b) * TT + t];
    vals[i] = v; mx = fmaxf(mx, v);
  }
  #pragma unroll
  for (int off = 32; off; off >>= 1) mx = fmaxf(mx, __shfl_xor(mx, off));
  if (lane == 0) sm[wid] = mx;
  __syncthreads();
  mx = fmaxf(fmaxf(sm[0], sm[1]), fmaxf(sm[2], sm[3]));
  float s = 0.f;
  #pragma unroll
  for (int i = 0; i < 16; ++i) { vals[i] = __expf(vals[i] - mx); s += vals[i]; }
  #pragma unroll
  for (int off = 32; off; off >>= 1) s += __shfl_xor(s, off);
  if (lane == 0) ssum[wid] = s;
  __syncthreads();
  s = ssum[0] + ssum[1] + ssum[2] + ssum[3];
  float inv = 1.f / s;
  #pragma unroll
  for (int i = 0; i < 16; ++i) a5[b * TT + tid + i * 256] = vals[i] * inv;
}

// --- D: a6[b,v] = values[b,v,:]·a5[b,:]  (one wave per output row) ---
__global__ void kOut(const float* __restrict__ values, const float* __restrict__ a5,
                     float* __restrict__ out) {
  int blk = blockIdx.x;
  int b = blk >> 7;
  int wid = threadIdx.x >> 6, lane = threadIdx.x & 63;
  int v = (blk & 127) * 4 + wid;
  const float* row = &values[((size_t)b * 512 + v) * TT];
  const float* w = &a5[b * TT];
  float s = 0.f;
  #pragma unroll
  for (int i = 0; i < 16; ++i) {
    int t = (i * 64 + lane) * 4;
    f32x4 x = *(const f32x4*)&row[t];
    f32x4 y = *(const f32x4*)&w[t];
    s += x.x * y.x + x.y * y.y + x.z * y.z + x.w * y.w;
  }
  #pragma unroll
  for (int off = 32; off; off >>= 1) s += __shfl_xor(s, off);
  if (lane == 0) out[b * 512 + v] = s;
}

extern "C" void kernel_launch(void* const* d_in, const int* in_sizes, int n_in,
                              void* d_out, int out_size, void* d_ws, size_t ws_size,
                              hipStream_t stream) {
  const float* query  = (const float*)d_in[0];
  const float* keys   = (const float*)d_in[1];
  const float* values = (const float*)d_in[2];
  const float* w42    = (const float*)d_in[3];
  const float* b4     = (const float*)d_in[4];
  const float* w54    = (const float*)d_in[5];
  // d_in[6] (b5) shifts n5 by a constant -> softmax-invariant; unused.
  float* out = (float*)d_out;

  char* ws = (char*)d_ws;
  unsigned short* W1bf = (unsigned short*)ws;                        // 512 KB
  float* qterm = (float*)(ws + 524288);                              // 64 KB
  float* n5p   = (float*)(ws + 524288 + 65536);                      // 2 MB  [4][B][T]
  float* a5    = (float*)(ws + 524288 + 65536 + 2097152);            // 512 KB

  kConv   <<<256, 256, 0, stream>>>(w42, W1bf);
  kQterm  <<<4096, 256, 0, stream>>>(w42, query, b4, qterm);
  kMain   <<<4096, 256, 0, stream>>>(keys, W1bf, qterm, w54, n5p);
  kSoftmax<<<32, 256, 0, stream>>>(n5p, a5);
  kOut    <<<4096, 256, 0, stream>>>(values, a5, out);
}

// Round 2
// 167.665 us; speedup vs baseline: 1.3725x; 1.3725x over previous
//
#include <hip/hip_runtime.h>
#include <hip/hip_bf16.h>
#include <cstdint>
#include <cstddef>

typedef __attribute__((ext_vector_type(4))) float f32x4;
typedef __attribute__((ext_vector_type(8))) short s16x8;
typedef __attribute__((ext_vector_type(4))) unsigned short u16x4;
typedef __attribute__((ext_vector_type(8))) unsigned short u16x8;

#define NB 32
#define DD 512
#define TT 4096
#define HH 512
#define TB 64     // t-tile per block
#define BK 32     // k per iteration
#define NKK 16    // 512/BK

__device__ __forceinline__ unsigned short f2bf(float f) {
  uint32_t u = __builtin_bit_cast(uint32_t, f);
  u += 0x7fffu + ((u >> 16) & 1u);   // RNE; inputs are normal floats
  return (unsigned short)(u >> 16);
}

__device__ __forceinline__ float tanh_fast(float x) {
  x = fminf(fmaxf(x, -15.f), 15.f);
  float e = __expf(2.f * x);
  return (e - 1.f) / (e + 1.f);
}

// --- A1: W1swz[kk][s][h] : 16B chunk = W1[h][kk*32 + s*8 .. +7] in bf16.
// Slot-major chunk layout makes kMain's A-fragment loads unit-stride.
__global__ void kConvT(const float* __restrict__ w42, u16x8* __restrict__ W1swz) {
  int g = blockIdx.x * 256 + threadIdx.x;        // 0..32767 chunks
  int h = g & 511, sk = g >> 9;                  // sk 0..63
  int kk = sk >> 2, s = sk & 3;
  const float* src = &w42[h * 1024 + kk * 32 + s * 8];
  f32x4 v0 = *reinterpret_cast<const f32x4*>(src);
  f32x4 v1 = *reinterpret_cast<const f32x4*>(src + 4);
  u16x8 c;
  c[0] = f2bf(v0.x); c[1] = f2bf(v0.y); c[2] = f2bf(v0.z); c[3] = f2bf(v0.w);
  c[4] = f2bf(v1.x); c[5] = f2bf(v1.y); c[6] = f2bf(v1.z); c[7] = f2bf(v1.w);
  W1swz[kk * 2048 + s * 512 + h] = c;
}

// --- A2: qterm[b,h] = w42[h,512:]·query[b] + b4[h]  (one wave per (b,h)) ---
__global__ void kQterm(const float* __restrict__ w42, const float* __restrict__ query,
                       const float* __restrict__ b4, float* __restrict__ qterm) {
  int wid = blockIdx.x * 4 + (threadIdx.x >> 6);
  int lane = threadIdx.x & 63;
  int b = wid >> 9, h = wid & 511;
  const float* wr = &w42[h * 1024 + 512];
  const float* q  = &query[b * 512];
  int d = lane * 8;
  f32x4 w0 = *(const f32x4*)&wr[d], w1 = *(const f32x4*)&wr[d + 4];
  f32x4 q0 = *(const f32x4*)&q[d],  q1 = *(const f32x4*)&q[d + 4];
  float s = w0.x*q0.x + w0.y*q0.y + w0.z*q0.z + w0.w*q0.w
          + w1.x*q1.x + w1.y*q1.y + w1.z*q1.z + w1.w*q1.w;
  #pragma unroll
  for (int off = 32; off; off >>= 1) s += __shfl_xor(s, off);
  if (lane == 0) qterm[b * 512 + h] = s + b4[h];
}

// --- B: fused  n5[b][t] = sum_h w54[h]*tanh(W1@keys + qterm)
// Block: full H=512 x TB=64 t.  4 waves, wave tile 128h x 64t.
// A-frags: registers direct from L2 (W1swz, slot-major).  B: keys f32 -> bf16
// in regs -> tiny double-buffered LDS (4KB/buf).  One raw barrier per K-step.
__global__ __launch_bounds__(256, 2) void kMain(
    const float* __restrict__ keys, const u16x8* __restrict__ W1swz,
    const float* __restrict__ qterm, const float* __restrict__ w54,
    float* __restrict__ n5) {
  __shared__ s16x8 Bs[2 * 4 * 64];   // [buf][slot][t] 16B chunks = 8 KB
  __shared__ float red[4][64];

  int bid = blockIdx.x;
  int b = bid >> 6, tblk = bid & 63;
  int t0 = tblk * TB;
  int tid = threadIdx.x, lane = tid & 63, w = tid >> 6;   // w = wave's h-quadrant
  int lr = lane & 15, lg = lane >> 4;

  // B-staging source: wave w loads k-rows w*8..w*8+7, t = t0+lane
  const float* kp = keys + (size_t)b * DD * TT + (size_t)(w * 8) * TT + t0 + lane;
  // A-frag source: chunk (kk, s=lg, h = w*128 + m*16 + lr)
  const s16x8* ap = reinterpret_cast<const s16x8*>(W1swz) + lg * 512 + w * 128 + lr;

  f32x4 acc[8][4];
  #pragma unroll
  for (int m = 0; m < 8; ++m)
    #pragma unroll
    for (int n = 0; n < 4; ++n) acc[m][n] = (f32x4){0.f, 0.f, 0.f, 0.f};

  float r[8];
  #pragma unroll
  for (int j = 0; j < 8; ++j) r[j] = kp[(size_t)j * TT];   // prologue B(0)

  for (int kk = 0; kk < NKK; ++kk) {
    // convert staged B regs -> bf16 chunk, write to this iter's buffer
    s16x8 c;
    #pragma unroll
    for (int j = 0; j < 8; ++j) c[j] = (short)f2bf(r[j]);
    Bs[((kk & 1) * 4 + w) * 64 + lane] = c;

    // issue this iter's A-fragment loads (L2-hot, ride across the barrier)
    s16x8 af[8];
    #pragma unroll
    for (int m = 0; m < 8; ++m) af[m] = ap[kk * 2048 + m * 16];

    // prefetch next B tile into regs (latency hides under MFMA phase)
    if (kk + 1 < NKK) {
      const float* kp2 = kp + (size_t)(kk + 1) * BK * TT;
      #pragma unroll
      for (int j = 0; j < 8; ++j) r[j] = kp2[(size_t)j * TT];
    }

    asm volatile("s_waitcnt lgkmcnt(0)" ::: "memory");  // Bs writes visible
    __builtin_amdgcn_s_barrier();                        // vmcnt NOT drained

    s16x8 bf[4];
    #pragma unroll
    for (int n = 0; n < 4; ++n)
      bf[n] = Bs[((kk & 1) * 4 + lg) * 64 + n * 16 + lr];

    #pragma unroll
    for (int m = 0; m < 8; ++m)
      #pragma unroll
      for (int n = 0; n < 4; ++n)
        acc[m][n] = __builtin_amdgcn_mfma_f32_16x16x32_bf16(af[m], bf[n], acc[m][n], 0, 0, 0);
  }

  // epilogue: tanh + w54-weighted reduce over this wave's 128 h
  float part[4] = {0.f, 0.f, 0.f, 0.f};
  int hb = w * 128;
  #pragma unroll
  for (int m = 0; m < 8; ++m) {
    #pragma unroll
    for (int rr = 0; rr < 4; ++rr) {
      int h = hb + m * 16 + lg * 4 + rr;     // C/D: row=(lane>>4)*4+reg
      float qv = qterm[b * HH + h];
      float wv = w54[h];
      #pragma unroll
      for (int n = 0; n < 4; ++n)
        part[n] += wv * tanh_fast(acc[m][n][rr] + qv);
    }
  }
  #pragma unroll
  for (int n = 0; n < 4; ++n) {
    part[n] += __shfl_xor(part[n], 16);
    part[n] += __shfl_xor(part[n], 32);
  }
  if (lane < 16) {
    #pragma unroll
    for (int n = 0; n < 4; ++n) red[w][n * 16 + lane] = part[n];
  }
  __syncthreads();
  if (tid < 64) {
    float v = red[0][tid] + red[1][tid] + red[2][tid] + red[3][tid];
    n5[b * TT + t0 + tid] = v;
  }
}

// --- C: softmax over T per batch (b5 cancels; omitted) ---
__global__ void kSoftmax(const float* __restrict__ n5, float* __restrict__ a5) {
  int b = blockIdx.x, tid = threadIdx.x;
  int lane = tid & 63, wid = tid >> 6;
  __shared__ float sm[4];
  __shared__ float ssum[4];
  float vals[16];
  float mx = -1e30f;
  #pragma unroll
  for (int i = 0; i < 16; ++i) {
    float v = n5[b * TT + tid + i * 256];
    vals[i] = v; mx = fmaxf(mx, v);
  }
  #pragma unroll
  for (int off = 32; off; off >>= 1) mx = fmaxf(mx, __shfl_xor(mx, off));
  if (lane == 0) sm[wid] = mx;
  __syncthreads();
  mx = fmaxf(fmaxf(sm[0], sm[1]), fmaxf(sm[2], sm[3]));
  float s = 0.f;
  #pragma unroll
  for (int i = 0; i < 16; ++i) { vals[i] = __expf(vals[i] - mx); s += vals[i]; }
  #pragma unroll
  for (int off = 32; off; off >>= 1) s += __shfl_xor(s, off);
  if (lane == 0) ssum[wid] = s;
  __syncthreads();
  s = ssum[0] + ssum[1] + ssum[2] + ssum[3];
  float inv = 1.f / s;
  #pragma unroll
  for (int i = 0; i < 16; ++i) a5[b * TT + tid + i * 256] = vals[i] * inv;
}

// --- D: a6[b,v] = values[b,v,:]·a5[b,:]  (one wave per output row) ---
__global__ void kOut(const float* __restrict__ values, const float* __restrict__ a5,
                     float* __restrict__ out) {
  int blk = blockIdx.x;
  int b = blk >> 7;
  int wid = threadIdx.x >> 6, lane = threadIdx.x & 63;
  int v = (blk & 127) * 4 + wid;
  const float* row = &values[((size_t)b * 512 + v) * TT];
  const float* wv = &a5[b * TT];
  float s = 0.f;
  #pragma unroll
  for (int i = 0; i < 16; ++i) {
    int t = (i * 64 + lane) * 4;
    f32x4 x = *(const f32x4*)&row[t];
    f32x4 y = *(const f32x4*)&wv[t];
    s += x.x * y.x + x.y * y.y + x.z * y.z + x.w * y.w;
  }
  #pragma unroll
  for (int off = 32; off; off >>= 1) s += __shfl_xor(s, off);
  if (lane == 0) out[b * 512 + v] = s;
}

extern "C" void kernel_launch(void* const* d_in, const int* in_sizes, int n_in,
                              void* d_out, int out_size, void* d_ws, size_t ws_size,
                              hipStream_t stream) {
  const float* query  = (const float*)d_in[0];
  const float* keys   = (const float*)d_in[1];
  const float* values = (const float*)d_in[2];
  const float* w42    = (const float*)d_in[3];
  const float* b4     = (const float*)d_in[4];
  const float* w54    = (const float*)d_in[5];
  // d_in[6] (b5) shifts n5 by a constant -> softmax-invariant; unused.
  float* out = (float*)d_out;

  char* ws = (char*)d_ws;
  u16x8* W1swz = (u16x8*)ws;                               // 512 KB
  float* qterm = (float*)(ws + 524288);                    // 64 KB
  float* n5    = (float*)(ws + 524288 + 65536);            // 512 KB
  float* a5    = (float*)(ws + 524288 + 65536 + 524288);   // 512 KB

  kConvT  <<<128, 256, 0, stream>>>(w42, W1swz);
  kQterm  <<<4096, 256, 0, stream>>>(w42, query, b4, qterm);
  kMain   <<<2048, 256, 0, stream>>>(keys, W1swz, qterm, w54, n5);
  kSoftmax<<<32, 256, 0, stream>>>(n5, a5);
  kOut    <<<4096, 256, 0, stream>>>(values, a5, out);
}